// Round 5
// baseline (859.899 us; speedup 1.0000x reference)
//
#include <hip/hip_runtime.h>
#include <hip/hip_bf16.h>
#include <math.h>

typedef __attribute__((ext_vector_type(8))) short bfrag8;
typedef __attribute__((ext_vector_type(4))) float ffrag4;

// ---------- helpers ----------
__device__ inline float bf2f(unsigned short h) { return __uint_as_float(((unsigned)h) << 16); }
__device__ inline unsigned short f2bf(float f) {
    unsigned u = __float_as_uint(f);
    unsigned r = (u + 0x7FFFu + ((u >> 16) & 1u)) >> 16;
    return (unsigned short)r;
}
__device__ inline float wred(float v) {
    v += __shfl_xor(v, 1, 64);
    v += __shfl_xor(v, 2, 64);
    v += __shfl_xor(v, 4, 64);
    v += __shfl_xor(v, 8, 64);
    v += __shfl_xor(v, 16, 64);
    v += __shfl_xor(v, 32, 64);
    return v;
}
__device__ inline float wredmax(float v) {
    v = fmaxf(v, __shfl_xor(v, 1, 64));
    v = fmaxf(v, __shfl_xor(v, 2, 64));
    v = fmaxf(v, __shfl_xor(v, 4, 64));
    v = fmaxf(v, __shfl_xor(v, 8, 64));
    v = fmaxf(v, __shfl_xor(v, 16, 64));
    v = fmaxf(v, __shfl_xor(v, 32, 64));
    return v;
}
__device__ inline float bsum(float v, float* red) {
    v = wred(v);
    if ((threadIdx.x & 63) == 0) red[threadIdx.x >> 6] = v;
    __syncthreads();
    float r = red[0] + red[1] + red[2] + red[3];
    __syncthreads();
    return r;
}
__device__ inline float bmax(float v, float* red) {
    v = wredmax(v);
    if ((threadIdx.x & 63) == 0) red[threadIdx.x >> 6] = v;
    __syncthreads();
    float r = fmaxf(fmaxf(red[0], red[1]), fmaxf(red[2], red[3]));
    __syncthreads();
    return r;
}

#define ACLIP (1.0f - 1e-7f)

// ---------- dtype detection ----------
__global__ void k_detect(const unsigned short* __restrict__ hyper, int* __restrict__ flag) {
    __shared__ int total;
    int t = threadIdx.x;
    if (t == 0) total = 0;
    __syncthreads();
    int cnt = 0;
    for (int i = t * 8; i < t * 8 + 8; i++) {
        if ((i & 1) == 0) {
            unsigned e = ((unsigned)hyper[i] >> 7) & 0xFF;
            if (e >= 0xC0) cnt++;
        }
    }
    atomicAdd(&total, cnt);
    __syncthreads();
    if (t == 0) *flag = (total >= 32) ? 1 : 0;   // 1 = inputs are float32
}

// ---------- converters / fills ----------
__global__ void k_cvt(const void* __restrict__ s, float* __restrict__ d, int n,
                      const int* __restrict__ flag) {
    int i = blockIdx.x * blockDim.x + threadIdx.x;
    if (i >= n) return;
    if (*flag) d[i] = ((const float*)s)[i];
    else       d[i] = bf2f(((const unsigned short*)s)[i]);
}
__global__ void k_wsplit(const void* __restrict__ s, unsigned short* __restrict__ hi,
                         unsigned short* __restrict__ lo, int n, const int* __restrict__ flag) {
    int i = blockIdx.x * blockDim.x + threadIdx.x;
    if (i >= n) return;
    float x = (*flag) ? ((const float*)s)[i] : bf2f(((const unsigned short*)s)[i]);
    unsigned short h = f2bf(x);
    hi[i] = h;
    lo[i] = f2bf(x - bf2f(h));
}
__global__ void k_fill(unsigned* __restrict__ p, unsigned v, int n) {
    int i = blockIdx.x * blockDim.x + threadIdx.x;
    if (i < n) p[i] = v;
}

// ---------- CSR build ----------
__global__ void k_hist(const int* __restrict__ dst_idx, int* __restrict__ deg, int n_edge) {
    int i = blockIdx.x * blockDim.x + threadIdx.x;
    if (i < n_edge) atomicAdd(deg + dst_idx[i], 1);
}
__global__ __launch_bounds__(1024) void k_scan(const int* __restrict__ deg,
                                               int* __restrict__ rowptr,
                                               int* __restrict__ cursor, int n) {
    __shared__ int part[1024];
    int t = threadIdx.x;
    int chunk = (n + 1023) >> 10;
    int lo = t * chunk, hi = min(lo + chunk, n);
    int s = 0;
    for (int i = lo; i < hi; i++) s += deg[i];
    part[t] = s;
    __syncthreads();
    for (int dd = 1; dd < 1024; dd <<= 1) {
        int v = (t >= dd) ? part[t - dd] : 0;
        __syncthreads();
        part[t] += v;
        __syncthreads();
    }
    int base = (t == 0) ? 0 : part[t - 1];
    for (int i = lo; i < hi; i++) {
        rowptr[i] = base; cursor[i] = base;
        base += deg[i];
    }
    if (t == 0) rowptr[n] = part[1023];
}
__global__ void k_scatter_edges(const int* __restrict__ src_idx, const int* __restrict__ dst_idx,
                                int* __restrict__ cursor, int* __restrict__ es, int n_edge) {
    int i = blockIdx.x * blockDim.x + threadIdx.x;
    if (i >= n_edge) return;
    int slot = atomicAdd(cursor + dst_idx[i], 1);
    es[slot] = src_idx[i];
}

// ---------- stage 1: per-node prologue (wave per node) -> Ah/Al bf16 split ----------
__global__ void k_node_prep(const void* __restrict__ hyper_v,
                            const void* __restrict__ dt_v,
                            const float* __restrict__ tw, const float* __restrict__ tb,
                            unsigned short* __restrict__ Ah, unsigned short* __restrict__ Al,
                            float* __restrict__ tnode,
                            const int* __restrict__ flag, int n_dst, int n_total) {
    int wid  = (blockIdx.x * blockDim.x + threadIdx.x) >> 6;
    int lane = threadIdx.x & 63;
    if (wid >= n_total) return;
    int isf32 = *flag;
    float tval = 0.0f;
    if (wid >= n_dst) {
        int e = wid - n_dst;
        tval = isf32 ? ((const float*)dt_v)[e] : bf2f(((const unsigned short*)dt_v)[e]);
    }
    int j0 = lane * 2;
    float tf0 = cosf(tval * tw[j0]     + tb[j0]);
    float tf1 = cosf(tval * tw[j0 + 1] + tb[j0 + 1]);
    float h0, h1;
    if (isf32) {
        const float* hp = (const float*)hyper_v + (size_t)wid * 128 + j0;
        h0 = hp[0]; h1 = hp[1];
    } else {
        const unsigned short* hp = (const unsigned short*)hyper_v + (size_t)wid * 128 + j0;
        h0 = bf2f(hp[0]); h1 = bf2f(hp[1]);
    }
    float ptf2 = wred(tf0 * tf0 + tf1 * tf1);
    float ph2  = wred(h0 * h0 + h1 * h1);
    float pht  = wred(h0 * tf0 + h1 * tf1);
    float ntf = sqrtf(fmaxf(ptf2, 1e-30f));
    float maxn = 1.0f - 0.004f;
    float sc = (ntf > maxn) ? (maxn / ntf) : 1.0f;
    float y2 = sc * sc * ptf2, xy = sc * pht, x2 = ph2;
    float A = 1.0f + 2.0f * xy + y2;
    float B = 1.0f - x2;
    float iden = 1.0f / fmaxf(1.0f + 2.0f * xy + x2 * y2, 1e-15f);
    float s0 = (A * h0 + B * sc * tf0) * iden;
    float s1 = (A * h1 + B * sc * tf1) * iden;
    unsigned short h0s = f2bf(s0), h1s = f2bf(s1);
    unsigned short l0s = f2bf(s0 - bf2f(h0s)), l1s = f2bf(s1 - bf2f(h1s));
    *(ushort2*)(Ah + (size_t)wid * 128 + j0) = make_ushort2(h0s, h1s);
    *(ushort2*)(Al + (size_t)wid * 128 + j0) = make_ushort2(l0s, l1s);
    float ps2 = wred(s0 * s0 + s1 * s1);
    float xn = sqrtf(fmaxf(ps2, 1e-30f));
    float g = atanhf(fminf(xn, ACLIP)) / xn;
    if (lane == 0) tnode[wid] = g;
}

// ---------- stage 2+3 fused: split-bf16 MFMA GEMM (32 rows/wave) + epilogue ----------
// Each wave: 2 row-strips of 16 share every B fragment -> 6 MFMAs per bh/bl pair.
__global__ __launch_bounds__(256) void k_gemm_ep(
        const unsigned short* __restrict__ Ah, const unsigned short* __restrict__ Al,
        const unsigned short* __restrict__ Wh, const unsigned short* __restrict__ Wl,
        const float* __restrict__ bvec, const float* __restrict__ attn,
        const float* __restrict__ tnode,
        float* __restrict__ feat, float* __restrict__ x2a, float* __restrict__ ca,
        float* __restrict__ satt, int base, int M) {
    int w = threadIdx.x >> 6, lane = threadIdx.x & 63;
    int m16 = lane & 15, kg = lane >> 4;
    int rowbase = (blockIdx.x * 4 + w) * 32;
    int ar0 = min(rowbase + m16, M - 1);
    int ar1 = min(rowbase + 16 + m16, M - 1);
    ffrag4 acc[2][16];
#pragma unroll
    for (int p = 0; p < 2; p++)
#pragma unroll
        for (int ct = 0; ct < 16; ct++) acc[p][ct] = (ffrag4){0.0f, 0.0f, 0.0f, 0.0f};

    for (int ks = 0; ks < 4; ks++) {
        int k0 = ks * 32 + kg * 8;
        bfrag8 ah0 = *(const bfrag8*)(Ah + (size_t)ar0 * 128 + k0);
        bfrag8 al0 = *(const bfrag8*)(Al + (size_t)ar0 * 128 + k0);
        bfrag8 ah1 = *(const bfrag8*)(Ah + (size_t)ar1 * 128 + k0);
        bfrag8 al1 = *(const bfrag8*)(Al + (size_t)ar1 * 128 + k0);
#pragma unroll
        for (int ct = 0; ct < 16; ct++) {
            size_t wb = (size_t)(ct * 16 + m16) * 128 + k0;
            bfrag8 bh = *(const bfrag8*)(Wh + wb);
            bfrag8 bl = *(const bfrag8*)(Wl + wb);
            acc[0][ct] = __builtin_amdgcn_mfma_f32_16x16x32_bf16(ah0, bh, acc[0][ct], 0, 0, 0);
            acc[0][ct] = __builtin_amdgcn_mfma_f32_16x16x32_bf16(al0, bh, acc[0][ct], 0, 0, 0);
            acc[0][ct] = __builtin_amdgcn_mfma_f32_16x16x32_bf16(ah0, bl, acc[0][ct], 0, 0, 0);
            acc[1][ct] = __builtin_amdgcn_mfma_f32_16x16x32_bf16(ah1, bh, acc[1][ct], 0, 0, 0);
            acc[1][ct] = __builtin_amdgcn_mfma_f32_16x16x32_bf16(al1, bh, acc[1][ct], 0, 0, 0);
            acc[1][ct] = __builtin_amdgcn_mfma_f32_16x16x32_bf16(ah1, bl, acc[1][ct], 0, 0, 0);
        }
    }

    // epilogue in C-layout: lane holds rows kg*4+r, col ct*16+m16 (per strip p)
    float bv[16], av[16];
    float pb2 = 0.0f;
#pragma unroll
    for (int ct = 0; ct < 16; ct++) {
        bv[ct] = bvec[ct * 16 + m16];
        av[ct] = attn[ct * 16 + m16];
        pb2 += bv[ct] * bv[ct];
    }
#pragma unroll
    for (int off = 1; off < 16; off <<= 1) pb2 += __shfl_xor(pb2, off, 64);

#pragma unroll
    for (int p = 0; p < 2; p++) {
        float pm2[4] = {0, 0, 0, 0}, pdb[4] = {0, 0, 0, 0};
#pragma unroll
        for (int ct = 0; ct < 16; ct++)
#pragma unroll
            for (int r = 0; r < 4; r++) {
                float v = acc[p][ct][r];
                pm2[r] += v * v;
                pdb[r] += v * bv[ct];
            }
#pragma unroll
        for (int off = 1; off < 16; off <<= 1)
#pragma unroll
            for (int r = 0; r < 4; r++) {
                pm2[r] += __shfl_xor(pm2[r], off, 64);
                pdb[r] += __shfl_xor(pdb[r], off, 64);
            }
#pragma unroll
        for (int r = 0; r < 4; r++) {
            int row_o = rowbase + p * 16 + kg * 4 + r;
            bool ok = row_o < M;
            float g = ok ? tnode[base + row_o] : 1.0f;
            float mxn = sqrtf(fmaxf(pm2[r], 1e-30f));
            float sv = tanhf(mxn * g) / mxn;
            float xy = sv * pdb[r];
            float x2v = sv * sv * pm2[r];
            float Am = 1.0f + 2.0f * xy + pb2;
            float Bm = 1.0f - x2v;
            float iden = 1.0f / fmaxf(1.0f + 2.0f * xy + x2v * pb2, 1e-15f);
            float pf2 = 0.0f, pa0 = 0.0f, pa1 = 0.0f;
#pragma unroll
            for (int ct = 0; ct < 16; ct++) {
                float f = (Am * sv * acc[p][ct][r] + Bm * bv[ct]) * iden;
                acc[p][ct][r] = f;
                pf2 += f * f;
                if (ct < 8) pa0 += f * av[ct]; else pa1 += f * av[ct];
            }
#pragma unroll
            for (int off = 1; off < 16; off <<= 1) {
                pf2 += __shfl_xor(pf2, off, 64);
                pa0 += __shfl_xor(pa0, off, 64);
                pa1 += __shfl_xor(pa1, off, 64);
            }
            if (ok) {
                float* fr = feat + (size_t)(base + row_o) * 256;
#pragma unroll
                for (int ct = 0; ct < 16; ct++) fr[ct * 16 + m16] = acc[p][ct][r];
                if (m16 == 0) {
                    float nf = sqrtf(fmaxf(pf2, 1e-30f));
                    float cl = atanhf(fminf(nf, ACLIP)) / nf;
                    x2a[base + row_o] = pf2;
                    ca[base + row_o] = cl;
                    satt[(size_t)(base + row_o) * 2 + 0] = cl * pa0;
                    satt[(size_t)(base + row_o) * 2 + 1] = cl * pa1;
                }
            }
        }
    }
}

// ---------- stage 4+5 fused: per-dst distances + softmaxes + gather + expmap0 ----------
#define CAPR 48   // feat rows cached in LDS
#define CAPE 64   // edge scalars in LDS
__global__ __launch_bounds__(256) void k_aggregate(
        const int* __restrict__ rowptr, const int* __restrict__ es,
        const float* __restrict__ x2a, const float* __restrict__ satt,
        const float* __restrict__ ca, const float* __restrict__ feat,
        float* __restrict__ invg, float* __restrict__ w0g, float* __restrict__ w1g,
        void* __restrict__ out, const int* __restrict__ flag, int n_dst) {
    __shared__ float red[4];
    __shared__ float yrow[256];
    __shared__ float inv_s[CAPE], w0_s[CAPE], w1_s[CAPE];
    __shared__ int sb_s[CAPE];
    __shared__ float cache[CAPR * 256];
    int d = blockIdx.x;
    int t = threadIdx.x;
    int w = t >> 6, lane = t & 63;
    int off0 = rowptr[d], off1 = rowptr[d + 1];
    int deg = off1 - off0;
    if (deg == 0) {
        if (*flag) ((float*)out)[(size_t)d * 256 + t] = 0.0f;
        else ((unsigned short*)out)[(size_t)d * 256 + t] = 0;
        return;
    }
    yrow[t] = feat[(size_t)d * 256 + t];
    float y2 = x2a[d];
    __syncthreads();

    // pass A: per-edge dot + distance (wave per edge), cache feat rows
    int c = lane * 4;
    for (int b = 0; b < deg; b += 4) {
        int j = b + w;
        if (j < deg) {
            int i = off0 + j;
            int s = es[i];
            float4 xv = *(const float4*)(feat + (size_t)s * 256 + c);
            float4 yv = *(const float4*)(&yrow[c]);
            float pd = wred(xv.x * yv.x + xv.y * yv.y + xv.z * yv.z + xv.w * yv.w);
            if (j < CAPR) *(float4*)&cache[j * 256 + c] = xv;
            if (lane == 0) {
                float x2 = x2a[s];
                float A = 1.0f - 2.0f * pd + y2;
                float B = 1.0f - x2;
                float iden = 1.0f / fmaxf(1.0f - 2.0f * pd + x2 * y2, 1e-15f);
                float p2 = fmaxf(A * A * x2 - 2.0f * A * B * pd + B * B * y2, 0.0f);
                float nrm = sqrtf(fmaxf(p2, 1e-30f)) * iden;
                float dd = 2.0f * atanhf(fminf(nrm, ACLIP));
                float iv = 1.0f / (1e-15f + dd);
                if (j < CAPE) { inv_s[j] = iv; sb_s[j] = s; }
                else { invg[i] = iv; }
            }
        }
    }
    __syncthreads();

    // softmax 1 over inv
    float m1 = -INFINITY;
    for (int j = t; j < deg; j += 256)
        m1 = fmaxf(m1, (j < CAPE) ? inv_s[j] : invg[off0 + j]);
    m1 = bmax(m1, red);
    float s1 = 0.0f;
    for (int j = t; j < deg; j += 256)
        s1 += expf(((j < CAPE) ? inv_s[j] : invg[off0 + j]) - m1);
    s1 = bsum(s1, red);
    float is1 = 1.0f / s1;
    float sd0 = satt[(size_t)d * 2 + 0], sd1 = satt[(size_t)d * 2 + 1];

    // pass B: logits e0/e1 (stored), then softmax 2
    float m20 = -INFINITY, m21 = -INFINITY;
    for (int j = t; j < deg; j += 256) {
        int s = (j < CAPE) ? sb_s[j] : es[off0 + j];
        float iv = (j < CAPE) ? inv_s[j] : invg[off0 + j];
        float dsm = expf(iv - m1) * is1;
        float e0 = (satt[(size_t)s * 2 + 0] + sd0) * dsm; e0 = (e0 > 0.0f) ? e0 : 0.2f * e0;
        float e1 = (satt[(size_t)s * 2 + 1] + sd1) * dsm; e1 = (e1 > 0.0f) ? e1 : 0.2f * e1;
        if (j < CAPE) { w0_s[j] = e0; w1_s[j] = e1; }
        else { w0g[off0 + j] = e0; w1g[off0 + j] = e1; }
        m20 = fmaxf(m20, e0); m21 = fmaxf(m21, e1);
    }
    m20 = bmax(m20, red); m21 = bmax(m21, red);
    float s20 = 0.0f, s21 = 0.0f;
    for (int j = t; j < deg; j += 256) {
        float e0 = (j < CAPE) ? w0_s[j] : w0g[off0 + j];
        float e1 = (j < CAPE) ? w1_s[j] : w1g[off0 + j];
        s20 += expf(e0 - m20); s21 += expf(e1 - m21);
    }
    s20 = bsum(s20, red); s21 = bsum(s21, red);
    float is20 = 1.0f / s20, is21 = 1.0f / s21;
    for (int j = t; j < deg; j += 256) {
        int s = (j < CAPE) ? sb_s[j] : es[off0 + j];
        float cs = ca[s];
        if (j < CAPE) {
            w0_s[j] = expf(w0_s[j] - m20) * is20 * cs;
            w1_s[j] = expf(w1_s[j] - m21) * is21 * cs;
        } else {
            w0g[off0 + j] = expf(w0g[off0 + j] - m20) * is20 * cs;
            w1g[off0 + j] = expf(w1g[off0 + j] - m21) * is21 * cs;
        }
    }
    __syncthreads();

    // pass C: weighted gather (rows from LDS cache, spill from global)
    int col = t, h = t >> 7;
    float acc = 0.0f;
    for (int j = 0; j < deg; j++) {
        float wgt;
        if (j < CAPE) wgt = h ? w1_s[j] : w0_s[j];
        else          wgt = h ? w1g[off0 + j] : w0g[off0 + j];
        float x;
        if (j < CAPR) x = cache[j * 256 + col];
        else {
            int s = (j < CAPE) ? sb_s[j] : es[off0 + j];
            x = feat[(size_t)s * 256 + col];
        }
        acc += wgt * x;
    }
    // expmap0 + store
    float p2 = bsum(acc * acc, red);
    float n = sqrtf(fmaxf(p2, 1e-30f));
    float sc = tanhf(n) / n;
    float o = acc * sc;
    if (*flag) ((float*)out)[(size_t)d * 256 + col] = o;
    else ((unsigned short*)out)[(size_t)d * 256 + col] = f2bf(o);
}

// ---------- host ----------
extern "C" void kernel_launch(void* const* d_in, const int* in_sizes, int n_in,
                              void* d_out, int out_size, void* d_ws, size_t ws_size,
                              hipStream_t stream) {
    const void* hyper  = d_in[0];
    const void* dt     = d_in[1];
    const void* time_w = d_in[2];
    const void* time_b = d_in[3];
    const void* w_src  = d_in[4];
    const void* b_src  = d_in[5];
    const void* w_dst  = d_in[6];
    const void* b_dst  = d_in[7];
    const void* attn   = d_in[8];
    const int* src_idx = (const int*)d_in[9];
    const int* dst_idx = (const int*)d_in[10];

    const int DIMN = 128, HD = 256;
    int n_edge  = in_sizes[1];
    int n_total = in_sizes[0] / DIMN;
    int n_dst   = n_total - n_edge;

    float* ws = (float*)d_ws;
    size_t off = 0;
    auto alloc = [&](size_t n) { float* p = ws + off; off += n; return p; };
    float* p_tw    = alloc(DIMN);
    float* p_tb    = alloc(DIMN);
    float* p_bsrc  = alloc(HD);
    float* p_bdst  = alloc(HD);
    float* p_attn  = alloc(HD);
    int*   p_flag  = (int*)alloc(4);
    unsigned short* p_whs = (unsigned short*)alloc((size_t)HD * DIMN / 2);
    unsigned short* p_wls = (unsigned short*)alloc((size_t)HD * DIMN / 2);
    unsigned short* p_whd = (unsigned short*)alloc((size_t)HD * DIMN / 2);
    unsigned short* p_wld = (unsigned short*)alloc((size_t)HD * DIMN / 2);
    unsigned short* p_ah = (unsigned short*)alloc((size_t)n_total * DIMN / 2);
    unsigned short* p_al = (unsigned short*)alloc((size_t)n_total * DIMN / 2);
    int* p_deg    = (int*)alloc(n_dst);
    int* p_rowptr = (int*)alloc(n_dst + 1);
    int* p_cursor = (int*)alloc(n_dst);
    int* p_es     = (int*)alloc(n_edge);
    float* p_inv  = alloc(n_edge);
    float* p_w0   = alloc(n_edge);
    float* p_w1   = alloc(n_edge);
    float* p_feat  = alloc((size_t)n_total * HD);
    float* p_tnode = alloc(n_total);
    float* p_call  = alloc(n_total);
    float* p_x2    = alloc(n_total);
    float* p_satt  = alloc((size_t)n_total * 2);
    (void)ws_size;

    const int TB = 256;
    auto cdiv = [](int a, int b) { return (a + b - 1) / b; };

    k_detect<<<1, TB, 0, stream>>>((const unsigned short*)hyper, p_flag);

    k_cvt<<<1, TB, 0, stream>>>(time_w, p_tw, DIMN, p_flag);
    k_cvt<<<1, TB, 0, stream>>>(time_b, p_tb, DIMN, p_flag);
    k_cvt<<<1, TB, 0, stream>>>(b_src, p_bsrc, HD, p_flag);
    k_cvt<<<1, TB, 0, stream>>>(b_dst, p_bdst, HD, p_flag);
    k_cvt<<<1, TB, 0, stream>>>(attn, p_attn, HD, p_flag);
    k_wsplit<<<cdiv(HD * DIMN, TB), TB, 0, stream>>>(w_src, p_whs, p_wls, HD * DIMN, p_flag);
    k_wsplit<<<cdiv(HD * DIMN, TB), TB, 0, stream>>>(w_dst, p_whd, p_wld, HD * DIMN, p_flag);

    k_fill<<<cdiv(n_dst, TB), TB, 0, stream>>>((unsigned*)p_deg, 0u, n_dst);
    k_hist<<<cdiv(n_edge, TB), TB, 0, stream>>>(dst_idx, p_deg, n_edge);
    k_scan<<<1, 1024, 0, stream>>>(p_deg, p_rowptr, p_cursor, n_dst);
    k_scatter_edges<<<cdiv(n_edge, TB), TB, 0, stream>>>(src_idx, dst_idx, p_cursor,
                                                         p_es, n_edge);

    k_node_prep<<<cdiv(n_total, 4), TB, 0, stream>>>(hyper, dt, p_tw, p_tb,
                                                     p_ah, p_al, p_tnode, p_flag,
                                                     n_dst, n_total);

    k_gemm_ep<<<cdiv(n_dst, 128), TB, 0, stream>>>(p_ah, p_al, p_whd, p_wld,
                                                   p_bdst, p_attn, p_tnode,
                                                   p_feat, p_x2, p_call, p_satt, 0, n_dst);
    k_gemm_ep<<<cdiv(n_edge, 128), TB, 0, stream>>>(p_ah + (size_t)n_dst * DIMN,
                                                    p_al + (size_t)n_dst * DIMN,
                                                    p_whs, p_wls,
                                                    p_bsrc, p_attn, p_tnode,
                                                    p_feat, p_x2, p_call, p_satt,
                                                    n_dst, n_edge);

    k_aggregate<<<n_dst, TB, 0, stream>>>(p_rowptr, p_es, p_x2, p_satt, p_call,
                                          p_feat, p_inv, p_w0, p_w1,
                                          d_out, p_flag, n_dst);
}

// Round 6
// 698.769 us; speedup vs baseline: 1.2306x; 1.2306x over previous
//
#include <hip/hip_runtime.h>
#include <hip/hip_bf16.h>
#include <math.h>

typedef __attribute__((ext_vector_type(8))) short bfrag8;
typedef __attribute__((ext_vector_type(4))) float ffrag4;

// ---------- helpers ----------
__device__ inline float bf2f(unsigned short h) { return __uint_as_float(((unsigned)h) << 16); }
__device__ inline unsigned short f2bf(float f) {
    unsigned u = __float_as_uint(f);
    unsigned r = (u + 0x7FFFu + ((u >> 16) & 1u)) >> 16;
    return (unsigned short)r;
}
__device__ inline float wred(float v) {
    v += __shfl_xor(v, 1, 64);
    v += __shfl_xor(v, 2, 64);
    v += __shfl_xor(v, 4, 64);
    v += __shfl_xor(v, 8, 64);
    v += __shfl_xor(v, 16, 64);
    v += __shfl_xor(v, 32, 64);
    return v;
}
__device__ inline float wredmax(float v) {
    v = fmaxf(v, __shfl_xor(v, 1, 64));
    v = fmaxf(v, __shfl_xor(v, 2, 64));
    v = fmaxf(v, __shfl_xor(v, 4, 64));
    v = fmaxf(v, __shfl_xor(v, 8, 64));
    v = fmaxf(v, __shfl_xor(v, 16, 64));
    v = fmaxf(v, __shfl_xor(v, 32, 64));
    return v;
}
__device__ inline float bsum(float v, float* red) {
    v = wred(v);
    if ((threadIdx.x & 63) == 0) red[threadIdx.x >> 6] = v;
    __syncthreads();
    float r = red[0] + red[1] + red[2] + red[3];
    __syncthreads();
    return r;
}

#define ACLIP (1.0f - 1e-7f)

// ---------- dtype detection ----------
__global__ void k_detect(const unsigned short* __restrict__ hyper, int* __restrict__ flag) {
    __shared__ int total;
    int t = threadIdx.x;
    if (t == 0) total = 0;
    __syncthreads();
    int cnt = 0;
    for (int i = t * 8; i < t * 8 + 8; i++) {
        if ((i & 1) == 0) {
            unsigned e = ((unsigned)hyper[i] >> 7) & 0xFF;
            if (e >= 0xC0) cnt++;
        }
    }
    atomicAdd(&total, cnt);
    __syncthreads();
    if (t == 0) *flag = (total >= 32) ? 1 : 0;   // 1 = inputs are float32
}

// ---------- fused small-param conversion ----------
__device__ inline float ldin(const void* s, int i, int isf32) {
    return isf32 ? ((const float*)s)[i] : bf2f(((const unsigned short*)s)[i]);
}
__global__ void k_params(const void* __restrict__ w_src, const void* __restrict__ w_dst,
                         const void* __restrict__ b_src, const void* __restrict__ b_dst,
                         const void* __restrict__ attn, const void* __restrict__ time_w,
                         const void* __restrict__ time_b,
                         unsigned short* __restrict__ whs, unsigned short* __restrict__ wls,
                         unsigned short* __restrict__ whd, unsigned short* __restrict__ wld,
                         float* __restrict__ bsrc, float* __restrict__ bdst,
                         float* __restrict__ pattn, float* __restrict__ tw,
                         float* __restrict__ tb, const int* __restrict__ flag, int nw) {
    int i = blockIdx.x * blockDim.x + threadIdx.x;
    int isf32 = *flag;
    if (i < nw) {
        float x = ldin(w_src, i, isf32);
        unsigned short h = f2bf(x);
        whs[i] = h; wls[i] = f2bf(x - bf2f(h));
        float y = ldin(w_dst, i, isf32);
        unsigned short g = f2bf(y);
        whd[i] = g; wld[i] = f2bf(y - bf2f(g));
    }
    if (i < 256) {
        bsrc[i] = ldin(b_src, i, isf32);
        bdst[i] = ldin(b_dst, i, isf32);
        pattn[i] = ldin(attn, i, isf32);
    }
    if (i < 128) {
        tw[i] = ldin(time_w, i, isf32);
        tb[i] = ldin(time_b, i, isf32);
    }
}
__global__ void k_fill(unsigned* __restrict__ p, unsigned v, int n) {
    int i = blockIdx.x * blockDim.x + threadIdx.x;
    if (i < n) p[i] = v;
}

// ---------- CSR build ----------
__global__ void k_hist(const int* __restrict__ dst_idx, int* __restrict__ deg, int n_edge) {
    int i = blockIdx.x * blockDim.x + threadIdx.x;
    if (i < n_edge) atomicAdd(deg + dst_idx[i], 1);
}
__global__ __launch_bounds__(1024) void k_scan(const int* __restrict__ deg,
                                               int* __restrict__ rowptr,
                                               int* __restrict__ cursor, int n) {
    __shared__ int part[1024];
    int t = threadIdx.x;
    int chunk = (n + 1023) >> 10;
    int lo = t * chunk, hi = min(lo + chunk, n);
    int s = 0;
    for (int i = lo; i < hi; i++) s += deg[i];
    part[t] = s;
    __syncthreads();
    for (int dd = 1; dd < 1024; dd <<= 1) {
        int v = (t >= dd) ? part[t - dd] : 0;
        __syncthreads();
        part[t] += v;
        __syncthreads();
    }
    int base = (t == 0) ? 0 : part[t - 1];
    for (int i = lo; i < hi; i++) {
        rowptr[i] = base; cursor[i] = base;
        base += deg[i];
    }
    if (t == 0) rowptr[n] = part[1023];
}
__global__ void k_scatter_edges(const int* __restrict__ src_idx, const int* __restrict__ dst_idx,
                                int* __restrict__ cursor, int* __restrict__ es, int n_edge) {
    int i = blockIdx.x * blockDim.x + threadIdx.x;
    if (i >= n_edge) return;
    int slot = atomicAdd(cursor + dst_idx[i], 1);
    es[slot] = src_idx[i];
}

// ---------- stage 1: per-node prologue (wave per node) -> Ah/Al bf16 split ----------
__global__ void k_node_prep(const void* __restrict__ hyper_v,
                            const void* __restrict__ dt_v,
                            const float* __restrict__ tw, const float* __restrict__ tb,
                            unsigned short* __restrict__ Ah, unsigned short* __restrict__ Al,
                            float* __restrict__ tnode,
                            const int* __restrict__ flag, int n_dst, int n_total) {
    int wid  = (blockIdx.x * blockDim.x + threadIdx.x) >> 6;
    int lane = threadIdx.x & 63;
    if (wid >= n_total) return;
    int isf32 = *flag;
    float tval = 0.0f;
    if (wid >= n_dst) {
        int e = wid - n_dst;
        tval = isf32 ? ((const float*)dt_v)[e] : bf2f(((const unsigned short*)dt_v)[e]);
    }
    int j0 = lane * 2;
    float tf0 = cosf(tval * tw[j0]     + tb[j0]);
    float tf1 = cosf(tval * tw[j0 + 1] + tb[j0 + 1]);
    float h0, h1;
    if (isf32) {
        const float* hp = (const float*)hyper_v + (size_t)wid * 128 + j0;
        h0 = hp[0]; h1 = hp[1];
    } else {
        const unsigned short* hp = (const unsigned short*)hyper_v + (size_t)wid * 128 + j0;
        h0 = bf2f(hp[0]); h1 = bf2f(hp[1]);
    }
    float ptf2 = wred(tf0 * tf0 + tf1 * tf1);
    float ph2  = wred(h0 * h0 + h1 * h1);
    float pht  = wred(h0 * tf0 + h1 * tf1);
    float ntf = sqrtf(fmaxf(ptf2, 1e-30f));
    float maxn = 1.0f - 0.004f;
    float sc = (ntf > maxn) ? (maxn / ntf) : 1.0f;
    float y2 = sc * sc * ptf2, xy = sc * pht, x2 = ph2;
    float A = 1.0f + 2.0f * xy + y2;
    float B = 1.0f - x2;
    float iden = 1.0f / fmaxf(1.0f + 2.0f * xy + x2 * y2, 1e-15f);
    float s0 = (A * h0 + B * sc * tf0) * iden;
    float s1 = (A * h1 + B * sc * tf1) * iden;
    unsigned short h0s = f2bf(s0), h1s = f2bf(s1);
    unsigned short l0s = f2bf(s0 - bf2f(h0s)), l1s = f2bf(s1 - bf2f(h1s));
    *(ushort2*)(Ah + (size_t)wid * 128 + j0) = make_ushort2(h0s, h1s);
    *(ushort2*)(Al + (size_t)wid * 128 + j0) = make_ushort2(l0s, l1s);
    float ps2 = wred(s0 * s0 + s1 * s1);
    float xn = sqrtf(fmaxf(ps2, 1e-30f));
    float g = atanhf(fminf(xn, ACLIP)) / xn;
    if (lane == 0) tnode[wid] = g;
}

// ---------- stage 2+3 fused: split-bf16 MFMA GEMM (32 rows/wave) + epilogue ----------
__global__ __launch_bounds__(256) void k_gemm_ep(
        const unsigned short* __restrict__ Ah, const unsigned short* __restrict__ Al,
        const unsigned short* __restrict__ Wh, const unsigned short* __restrict__ Wl,
        const float* __restrict__ bvec, const float* __restrict__ attn,
        const float* __restrict__ tnode,
        float* __restrict__ feat, float* __restrict__ x2a, float* __restrict__ ca,
        float* __restrict__ satt, int base, int M) {
    int w = threadIdx.x >> 6, lane = threadIdx.x & 63;
    int m16 = lane & 15, kg = lane >> 4;
    int rowbase = (blockIdx.x * 4 + w) * 32;
    int ar0 = min(rowbase + m16, M - 1);
    int ar1 = min(rowbase + 16 + m16, M - 1);
    ffrag4 acc[2][16];
#pragma unroll
    for (int p = 0; p < 2; p++)
#pragma unroll
        for (int ct = 0; ct < 16; ct++) acc[p][ct] = (ffrag4){0.0f, 0.0f, 0.0f, 0.0f};

    for (int ks = 0; ks < 4; ks++) {
        int k0 = ks * 32 + kg * 8;
        bfrag8 ah0 = *(const bfrag8*)(Ah + (size_t)ar0 * 128 + k0);
        bfrag8 al0 = *(const bfrag8*)(Al + (size_t)ar0 * 128 + k0);
        bfrag8 ah1 = *(const bfrag8*)(Ah + (size_t)ar1 * 128 + k0);
        bfrag8 al1 = *(const bfrag8*)(Al + (size_t)ar1 * 128 + k0);
#pragma unroll
        for (int ct = 0; ct < 16; ct++) {
            size_t wb = (size_t)(ct * 16 + m16) * 128 + k0;
            bfrag8 bh = *(const bfrag8*)(Wh + wb);
            bfrag8 bl = *(const bfrag8*)(Wl + wb);
            acc[0][ct] = __builtin_amdgcn_mfma_f32_16x16x32_bf16(ah0, bh, acc[0][ct], 0, 0, 0);
            acc[0][ct] = __builtin_amdgcn_mfma_f32_16x16x32_bf16(al0, bh, acc[0][ct], 0, 0, 0);
            acc[0][ct] = __builtin_amdgcn_mfma_f32_16x16x32_bf16(ah0, bl, acc[0][ct], 0, 0, 0);
            acc[1][ct] = __builtin_amdgcn_mfma_f32_16x16x32_bf16(ah1, bh, acc[1][ct], 0, 0, 0);
            acc[1][ct] = __builtin_amdgcn_mfma_f32_16x16x32_bf16(al1, bh, acc[1][ct], 0, 0, 0);
            acc[1][ct] = __builtin_amdgcn_mfma_f32_16x16x32_bf16(ah1, bl, acc[1][ct], 0, 0, 0);
        }
    }

    float bv[16], av[16];
    float pb2 = 0.0f;
#pragma unroll
    for (int ct = 0; ct < 16; ct++) {
        bv[ct] = bvec[ct * 16 + m16];
        av[ct] = attn[ct * 16 + m16];
        pb2 += bv[ct] * bv[ct];
    }
#pragma unroll
    for (int off = 1; off < 16; off <<= 1) pb2 += __shfl_xor(pb2, off, 64);

#pragma unroll
    for (int p = 0; p < 2; p++) {
        float pm2[4] = {0, 0, 0, 0}, pdb[4] = {0, 0, 0, 0};
#pragma unroll
        for (int ct = 0; ct < 16; ct++)
#pragma unroll
            for (int r = 0; r < 4; r++) {
                float v = acc[p][ct][r];
                pm2[r] += v * v;
                pdb[r] += v * bv[ct];
            }
#pragma unroll
        for (int off = 1; off < 16; off <<= 1)
#pragma unroll
            for (int r = 0; r < 4; r++) {
                pm2[r] += __shfl_xor(pm2[r], off, 64);
                pdb[r] += __shfl_xor(pdb[r], off, 64);
            }
#pragma unroll
        for (int r = 0; r < 4; r++) {
            int row_o = rowbase + p * 16 + kg * 4 + r;
            bool ok = row_o < M;
            float g = ok ? tnode[base + row_o] : 1.0f;
            float mxn = sqrtf(fmaxf(pm2[r], 1e-30f));
            float sv = tanhf(mxn * g) / mxn;
            float xy = sv * pdb[r];
            float x2v = sv * sv * pm2[r];
            float Am = 1.0f + 2.0f * xy + pb2;
            float Bm = 1.0f - x2v;
            float iden = 1.0f / fmaxf(1.0f + 2.0f * xy + x2v * pb2, 1e-15f);
            float pf2 = 0.0f, pa0 = 0.0f, pa1 = 0.0f;
#pragma unroll
            for (int ct = 0; ct < 16; ct++) {
                float f = (Am * sv * acc[p][ct][r] + Bm * bv[ct]) * iden;
                acc[p][ct][r] = f;
                pf2 += f * f;
                if (ct < 8) pa0 += f * av[ct]; else pa1 += f * av[ct];
            }
#pragma unroll
            for (int off = 1; off < 16; off <<= 1) {
                pf2 += __shfl_xor(pf2, off, 64);
                pa0 += __shfl_xor(pa0, off, 64);
                pa1 += __shfl_xor(pa1, off, 64);
            }
            if (ok) {
                float* fr = feat + (size_t)(base + row_o) * 256;
#pragma unroll
                for (int ct = 0; ct < 16; ct++) fr[ct * 16 + m16] = acc[p][ct][r];
                if (m16 == 0) {
                    float nf = sqrtf(fmaxf(pf2, 1e-30f));
                    float cl = atanhf(fminf(nf, ACLIP)) / nf;
                    x2a[base + row_o] = pf2;
                    ca[base + row_o] = cl;
                    satt[(size_t)(base + row_o) * 2 + 0] = cl * pa0;
                    satt[(size_t)(base + row_o) * 2 + 1] = cl * pa1;
                }
            }
        }
    }
}

// ---------- stage 4+5 fused: per-dst distances + softmaxes + gather + expmap0 ----------
// CAPR=16: LDS ~18.5 KB -> ~8 blocks/CU. Scalar softmax phases: wave 0 only,
// lane-parallel shuffle reductions (no block barriers).
#define CAPR 16
#define CAPE 64
__global__ __launch_bounds__(256) void k_aggregate(
        const int* __restrict__ rowptr, const int* __restrict__ es,
        const float* __restrict__ x2a, const float* __restrict__ satt,
        const float* __restrict__ ca, const float* __restrict__ feat,
        float* __restrict__ invg, float* __restrict__ w0g, float* __restrict__ w1g,
        void* __restrict__ out, const int* __restrict__ flag, int n_dst) {
    __shared__ float red[4];
    __shared__ float yrow[256];
    __shared__ float inv_s[CAPE], w0_s[CAPE], w1_s[CAPE];
    __shared__ int sb_s[CAPE];
    __shared__ float cache[CAPR * 256];
    int d = blockIdx.x;
    int t = threadIdx.x;
    int w = t >> 6, lane = t & 63;
    int off0 = rowptr[d], off1 = rowptr[d + 1];
    int deg = off1 - off0;
    if (deg == 0) {
        if (*flag) ((float*)out)[(size_t)d * 256 + t] = 0.0f;
        else ((unsigned short*)out)[(size_t)d * 256 + t] = 0;
        return;
    }
    yrow[t] = feat[(size_t)d * 256 + t];
    float y2 = x2a[d];
    __syncthreads();

    // pass A: per-edge dot + distance (wave per edge, 4 at a time); cache rows
    int c = lane * 4;
    float4 yv = *(const float4*)(&yrow[c]);
    for (int b = 0; b < deg; b += 4) {
        int j = b + w;
        if (j < deg) {
            int i = off0 + j;
            int s = es[i];
            float4 xv = *(const float4*)(feat + (size_t)s * 256 + c);
            float pd = wred(xv.x * yv.x + xv.y * yv.y + xv.z * yv.z + xv.w * yv.w);
            if (j < CAPR) *(float4*)&cache[j * 256 + c] = xv;
            if (lane == 0) {
                float x2 = x2a[s];
                float A = 1.0f - 2.0f * pd + y2;
                float B = 1.0f - x2;
                float iden = 1.0f / fmaxf(1.0f - 2.0f * pd + x2 * y2, 1e-15f);
                float p2 = fmaxf(A * A * x2 - 2.0f * A * B * pd + B * B * y2, 0.0f);
                float nrm = sqrtf(fmaxf(p2, 1e-30f)) * iden;
                float dd = 2.0f * atanhf(fminf(nrm, ACLIP));
                float iv = 1.0f / (1e-15f + dd);
                if (j < CAPE) { inv_s[j] = iv; sb_s[j] = s; }
                else { invg[i] = iv; }
            }
        }
    }
    __syncthreads();

    // scalar phases: wave 0 only, shuffle reductions
    if (w == 0) {
        float sd0 = satt[(size_t)d * 2 + 0], sd1 = satt[(size_t)d * 2 + 1];
        float lm = -INFINITY;
        for (int j = lane; j < deg; j += 64)
            lm = fmaxf(lm, (j < CAPE) ? inv_s[j] : invg[off0 + j]);
        float m1 = wredmax(lm);
        float ls = 0.0f;
        for (int j = lane; j < deg; j += 64)
            ls += expf(((j < CAPE) ? inv_s[j] : invg[off0 + j]) - m1);
        float is1 = 1.0f / wred(ls);
        float lm0 = -INFINITY, lm1 = -INFINITY;
        for (int j = lane; j < deg; j += 64) {
            int s = (j < CAPE) ? sb_s[j] : es[off0 + j];
            float iv = (j < CAPE) ? inv_s[j] : invg[off0 + j];
            float dsm = expf(iv - m1) * is1;
            float e0 = (satt[(size_t)s * 2 + 0] + sd0) * dsm; e0 = (e0 > 0.0f) ? e0 : 0.2f * e0;
            float e1 = (satt[(size_t)s * 2 + 1] + sd1) * dsm; e1 = (e1 > 0.0f) ? e1 : 0.2f * e1;
            if (j < CAPE) { w0_s[j] = e0; w1_s[j] = e1; }
            else { w0g[off0 + j] = e0; w1g[off0 + j] = e1; }
            lm0 = fmaxf(lm0, e0); lm1 = fmaxf(lm1, e1);
        }
        float m20 = wredmax(lm0), m21 = wredmax(lm1);
        float l20 = 0.0f, l21 = 0.0f;
        for (int j = lane; j < deg; j += 64) {
            float e0 = (j < CAPE) ? w0_s[j] : w0g[off0 + j];
            float e1 = (j < CAPE) ? w1_s[j] : w1g[off0 + j];
            l20 += expf(e0 - m20); l21 += expf(e1 - m21);
        }
        float is20 = 1.0f / wred(l20), is21 = 1.0f / wred(l21);
        for (int j = lane; j < deg; j += 64) {
            int s = (j < CAPE) ? sb_s[j] : es[off0 + j];
            float cs = ca[s];
            if (j < CAPE) {
                w0_s[j] = expf(w0_s[j] - m20) * is20 * cs;
                w1_s[j] = expf(w1_s[j] - m21) * is21 * cs;
            } else {
                w0g[off0 + j] = expf(w0g[off0 + j] - m20) * is20 * cs;
                w1g[off0 + j] = expf(w1g[off0 + j] - m21) * is21 * cs;
            }
        }
    }
    __syncthreads();

    // pass C: weighted gather (rows from LDS cache, spill from L2-hot global)
    int col = t, h = t >> 7;
    float acc = 0.0f;
    for (int j = 0; j < deg; j++) {
        float wgt = (j < CAPE) ? (h ? w1_s[j] : w0_s[j])
                               : (h ? w1g[off0 + j] : w0g[off0 + j]);
        float x;
        if (j < CAPR) x = cache[j * 256 + col];
        else {
            int s = (j < CAPE) ? sb_s[j] : es[off0 + j];
            x = feat[(size_t)s * 256 + col];
        }
        acc += wgt * x;
    }
    float p2 = bsum(acc * acc, red);
    float n = sqrtf(fmaxf(p2, 1e-30f));
    float sc = tanhf(n) / n;
    float o = acc * sc;
    if (*flag) ((float*)out)[(size_t)d * 256 + col] = o;
    else ((unsigned short*)out)[(size_t)d * 256 + col] = f2bf(o);
}

// ---------- host ----------
extern "C" void kernel_launch(void* const* d_in, const int* in_sizes, int n_in,
                              void* d_out, int out_size, void* d_ws, size_t ws_size,
                              hipStream_t stream) {
    const void* hyper  = d_in[0];
    const void* dt     = d_in[1];
    const void* time_w = d_in[2];
    const void* time_b = d_in[3];
    const void* w_src  = d_in[4];
    const void* b_src  = d_in[5];
    const void* w_dst  = d_in[6];
    const void* b_dst  = d_in[7];
    const void* attn   = d_in[8];
    const int* src_idx = (const int*)d_in[9];
    const int* dst_idx = (const int*)d_in[10];

    const int DIMN = 128, HD = 256;
    int n_edge  = in_sizes[1];
    int n_total = in_sizes[0] / DIMN;
    int n_dst   = n_total - n_edge;

    float* ws = (float*)d_ws;
    size_t off = 0;
    auto alloc = [&](size_t n) { float* p = ws + off; off += n; return p; };
    float* p_tw    = alloc(DIMN);
    float* p_tb    = alloc(DIMN);
    float* p_bsrc  = alloc(HD);
    float* p_bdst  = alloc(HD);
    float* p_attn  = alloc(HD);
    int*   p_flag  = (int*)alloc(4);
    unsigned short* p_whs = (unsigned short*)alloc((size_t)HD * DIMN / 2);
    unsigned short* p_wls = (unsigned short*)alloc((size_t)HD * DIMN / 2);
    unsigned short* p_whd = (unsigned short*)alloc((size_t)HD * DIMN / 2);
    unsigned short* p_wld = (unsigned short*)alloc((size_t)HD * DIMN / 2);
    unsigned short* p_ah = (unsigned short*)alloc((size_t)n_total * DIMN / 2);
    unsigned short* p_al = (unsigned short*)alloc((size_t)n_total * DIMN / 2);
    int* p_deg    = (int*)alloc(n_dst);
    int* p_rowptr = (int*)alloc(n_dst + 1);
    int* p_cursor = (int*)alloc(n_dst);
    int* p_es     = (int*)alloc(n_edge);
    float* p_inv  = alloc(n_edge);
    float* p_w0   = alloc(n_edge);
    float* p_w1   = alloc(n_edge);
    float* p_feat  = alloc((size_t)n_total * HD);
    float* p_tnode = alloc(n_total);
    float* p_call  = alloc(n_total);
    float* p_x2    = alloc(n_total);
    float* p_satt  = alloc((size_t)n_total * 2);
    (void)ws_size;

    const int TB = 256;
    auto cdiv = [](int a, int b) { return (a + b - 1) / b; };

    k_detect<<<1, TB, 0, stream>>>((const unsigned short*)hyper, p_flag);

    k_params<<<cdiv(HD * DIMN, TB), TB, 0, stream>>>(
        w_src, w_dst, b_src, b_dst, attn, time_w, time_b,
        p_whs, p_wls, p_whd, p_wld, p_bsrc, p_bdst, p_attn, p_tw, p_tb,
        p_flag, HD * DIMN);

    k_fill<<<cdiv(n_dst, TB), TB, 0, stream>>>((unsigned*)p_deg, 0u, n_dst);
    k_hist<<<cdiv(n_edge, TB), TB, 0, stream>>>(dst_idx, p_deg, n_edge);
    k_scan<<<1, 1024, 0, stream>>>(p_deg, p_rowptr, p_cursor, n_dst);
    k_scatter_edges<<<cdiv(n_edge, TB), TB, 0, stream>>>(src_idx, dst_idx, p_cursor,
                                                         p_es, n_edge);

    k_node_prep<<<cdiv(n_total, 4), TB, 0, stream>>>(hyper, dt, p_tw, p_tb,
                                                     p_ah, p_al, p_tnode, p_flag,
                                                     n_dst, n_total);

    k_gemm_ep<<<cdiv(n_dst, 128), TB, 0, stream>>>(p_ah, p_al, p_whd, p_wld,
                                                   p_bdst, p_attn, p_tnode,
                                                   p_feat, p_x2, p_call, p_satt, 0, n_dst);
    k_gemm_ep<<<cdiv(n_edge, 128), TB, 0, stream>>>(p_ah + (size_t)n_dst * DIMN,
                                                    p_al + (size_t)n_dst * DIMN,
                                                    p_whs, p_wls,
                                                    p_bsrc, p_attn, p_tnode,
                                                    p_feat, p_x2, p_call, p_satt,
                                                    n_dst, n_edge);

    k_aggregate<<<n_dst, TB, 0, stream>>>(p_rowptr, p_es, p_x2, p_satt, p_call,
                                          p_feat, p_inv, p_w0, p_w1,
                                          d_out, p_flag, n_dst);
}